// Round 5
// baseline (175.212 us; speedup 1.0000x reference)
//
#include <hip/hip_runtime.h>

#define NB 8
#define CH 128
#define HV 64
#define WV 64
#define HO 128
#define WO 128
#define KK 9

// ======================= fused kernel: att + gather =========================
// block = (b, value row h): 8*64 = 512 blocks x 256 threads (4 waves), 2/CU.
//
// Phase 1 (proven la_att v4 body): 1 out-px/thread over the block's 256 px
//   (out rows 2h, 2h+1 x cols 0..127). Weights wave-uniform -> scalar s_load,
//   SGPR operands for v_fmac. Residual folded by peeling channels 0..8.
//   att -> 10 KB LDS (no HBM round-trip, no 2nd launch).
//
// Phase 2 (proven v6 shuffle gather): lane = value column (WV=64 = wave),
//   wave w owns channels w*32..w*32+31. Per channel: 3 coalesced 256B row
//   loads; +-1 col neighbors via __shfl_up/down(.,1) whose edge-lane
//   keep-own semantics implement the replication clamp for free. 4-channel
//   software chunks keep 12 loads in flight. att (36 vals/lane) read from
//   LDS once, reused across all 32 channels.
#define SATT 10   // att LDS row stride (floats)
__global__ __launch_bounds__(256)
void la_fused2(const float* __restrict__ guide,   // [8,128,128,128]
               const float* __restrict__ value,   // [8,128,64,64]
               const float* __restrict__ wconv,   // [9,128]
               const float* __restrict__ bconv,   // [9]
               float* __restrict__ out)           // [8,128,128,128]
{
    __shared__ float s_att[256 * SATT];

    const int tid = threadIdx.x;
    const int blk = blockIdx.x;
    const int h   = blk & 63;            // value row
    const int b   = blk >> 6;            // batch

    // ---------------- phase 1: attention for out rows 2h, 2h+1 ----------------
    {
        const int col = tid & 127;                 // out col
        const int row = 2 * h + (tid >> 7);        // out row
        const float* gpix = guide + ((size_t)b * CH) * (HO * WO) + row * WO + col;

        float a[KK];
        #pragma unroll
        for (int k = 0; k < KK; ++k)
            a[k] = bconv[k];                       // uniform -> s_load

        // peeled channels 0..8: conv + residual (a[c] += g), k==c compile-time
        #pragma unroll
        for (int c = 0; c < KK; ++c) {
            float g = gpix[(size_t)c * (HO * WO)];
            #pragma unroll
            for (int k = 0; k < KK; ++k)
                a[k] += g * wconv[k * CH + c];     // uniform -> SGPR operand
            a[c] += g;
        }
        // channels 9..127: pure conv, weights via scalar pipe
        #pragma unroll 8
        for (int c = KK; c < CH; ++c) {
            float g = gpix[(size_t)c * (HO * WO)];
            #pragma unroll
            for (int k = 0; k < KK; ++k)
                a[k] += g * wconv[k * CH + c];
        }

        float m = a[0];
        #pragma unroll
        for (int k = 1; k < KK; ++k) m = fmaxf(m, a[k]);
        float s = 0.f;
        #pragma unroll
        for (int k = 0; k < KK; ++k) { a[k] = __expf(a[k] - m); s += a[k]; }
        float r = 1.0f / s;

        float* ap = &s_att[tid * SATT];
        #pragma unroll
        for (int k = 0; k < KK; ++k)
            ap[k] = a[k] * r;
    }

    __syncthreads();

    // ---------------- phase 2: weighted 3x3 gather, upsampled x2 ----------------
    const int lane = tid & 63;            // value column w
    const int wv   = tid >> 6;            // wave 0..3 -> channel group of 32

    // att for the 4 out px (2h,2h+1) x (2*lane, 2*lane+1), from LDS
    float a00[KK], a01[KK], a10[KK], a11[KK];
    {
        const float* p00 = &s_att[(2 * lane) * SATT];
        const float* p01 = &s_att[(2 * lane + 1) * SATT];
        const float* p10 = &s_att[(128 + 2 * lane) * SATT];
        const float* p11 = &s_att[(128 + 2 * lane + 1) * SATT];
        #pragma unroll
        for (int k = 0; k < KK; ++k) {
            a00[k] = p00[k]; a01[k] = p01[k];
            a10[k] = p10[k]; a11[k] = p11[k];
        }
    }

    const int hm = (h > 0) ? h - 1 : 0;            // replication clamp, rows
    const int hp = (h < HV - 1) ? h + 1 : HV - 1;
    const int cbase = wv * 32;
    const float* vc  = value + ((size_t)b * CH + cbase) * (HV * WV) + lane;
    const float* prm = vc + hm * WV;
    const float* pr0 = vc + h  * WV;
    const float* prp = vc + hp * WV;
    float* ob = out + (((size_t)b * CH + cbase) * HO + 2 * h) * WO + 2 * lane;

    for (int c4 = 0; c4 < 32; c4 += 4) {
        // issue 12 independent loads
        float vm[4], v0[4], vp[4];
        #pragma unroll
        for (int j = 0; j < 4; ++j) {
            size_t off = (size_t)(c4 + j) * (HV * WV);
            vm[j] = prm[off];
            v0[j] = pr0[off];
            vp[j] = prp[off];
        }
        // compute + store 4 channels
        #pragma unroll
        for (int j = 0; j < 4; ++j) {
            float tm = vm[j], t0 = v0[j], tp = vp[j];
            float tmL = __shfl_up(tm, 1), tmR = __shfl_down(tm, 1);
            float t0L = __shfl_up(t0, 1), t0R = __shfl_down(t0, 1);
            float tpL = __shfl_up(tp, 1), tpR = __shfl_down(tp, 1);

            float s00 = tmL*a00[0] + tm*a00[1] + tmR*a00[2]
                      + t0L*a00[3] + t0*a00[4] + t0R*a00[5]
                      + tpL*a00[6] + tp*a00[7] + tpR*a00[8];
            float s01 = tmL*a01[0] + tm*a01[1] + tmR*a01[2]
                      + t0L*a01[3] + t0*a01[4] + t0R*a01[5]
                      + tpL*a01[6] + tp*a01[7] + tpR*a01[8];
            float s10 = tmL*a10[0] + tm*a10[1] + tmR*a10[2]
                      + t0L*a10[3] + t0*a10[4] + t0R*a10[5]
                      + tpL*a10[6] + tp*a10[7] + tpR*a10[8];
            float s11 = tmL*a11[0] + tm*a11[1] + tmR*a11[2]
                      + t0L*a11[3] + t0*a11[4] + t0R*a11[5]
                      + tpL*a11[6] + tp*a11[7] + tpR*a11[8];

            float* oc = ob + (size_t)(c4 + j) * (HO * WO);
            float2 r0; r0.x = s00; r0.y = s01;
            float2 r1; r1.x = s10; r1.y = s11;
            *(float2*)oc        = r0;   // out row 2h
            *(float2*)(oc + WO) = r1;   // out row 2h+1
        }
    }
}

extern "C" void kernel_launch(void* const* d_in, const int* in_sizes, int n_in,
                              void* d_out, int out_size, void* d_ws, size_t ws_size,
                              hipStream_t stream) {
    const float* guide = (const float*)d_in[0];
    const float* value = (const float*)d_in[1];
    const float* wconv = (const float*)d_in[2];
    const float* bconv = (const float*)d_in[3];
    float* outp = (float*)d_out;
    (void)in_sizes; (void)n_in; (void)out_size; (void)d_ws; (void)ws_size;

    la_fused2<<<dim3(NB * HV), dim3(256), 0, stream>>>(guide, value, wconv, bconv, outp);
}

// Round 6
// 153.577 us; speedup vs baseline: 1.1409x; 1.1409x over previous
//
#include <hip/hip_runtime.h>

#define NB 8
#define CH 128
#define HV 64
#define WV 64
#define HO 128
#define WO 128
#define KK 9

// ======================= kernel A: attention (softmax) =======================
// v5: 4-way channel split to break the 2048-wave grid cap (was 8 waves/CU,
// latency-bound at 35.9 us vs 11.4 us floor — R5 decomposition).
// Block = 64 contiguous out-px x 4 waves; wave q accumulates channels
// 32q..32q+31 (32 coalesced 256B loads/thread, weights via scalar pipe);
// residual peel (att += guide[:, :K]) lives in q==0. LDS partial reduce
// (stride 40, float4 epilogue reads), wave 0 does softmax + stores.
// 2048 blocks x 256 thr = 8192 waves = 32/CU.
#define ASTR 40
__global__ __launch_bounds__(256)
void la_att(const float* __restrict__ guide,   // [8,128,128,128]
            const float* __restrict__ wconv,   // [9,128]
            const float* __restrict__ bconv,   // [9]
            float* __restrict__ att)           // [8,9,128,128] (workspace)
{
    __shared__ float s_part[64 * ASTR];

    const int tid = threadIdx.x;
    const int lpx = tid & 63;                 // pixel within block
    const int q   = tid >> 6;                 // wave = channel quarter 0..3
    const int p   = blockIdx.x * 64 + lpx;    // global pixel over (b,ho,wo)
    const int wo = p & 127;
    const int ho = (p >> 7) & 127;
    const int b  = p >> 14;

    const float* gpix = guide + ((size_t)b * CH) * (HO * WO) + ho * WO + wo;

    float a[KK];
    #pragma unroll
    for (int k = 0; k < KK; ++k) a[k] = 0.f;

    if (q == 0) {
        // peeled channels 0..8: conv + residual (a[c] += g), k==c compile-time
        #pragma unroll
        for (int c = 0; c < KK; ++c) {
            float g = gpix[(size_t)c * (HO * WO)];
            #pragma unroll
            for (int k = 0; k < KK; ++k)
                a[k] += g * wconv[k * CH + c];     // uniform -> SGPR operand
            a[c] += g;
        }
        #pragma unroll 8
        for (int c = KK; c < 32; ++c) {
            float g = gpix[(size_t)c * (HO * WO)];
            #pragma unroll
            for (int k = 0; k < KK; ++k)
                a[k] += g * wconv[k * CH + c];
        }
    } else {
        const int cbeg = q * 32;                   // wave-uniform
        #pragma unroll 8
        for (int c0 = 0; c0 < 32; ++c0) {
            float g = gpix[(size_t)(cbeg + c0) * (HO * WO)];
            #pragma unroll
            for (int k = 0; k < KK; ++k)
                a[k] += g * wconv[k * CH + cbeg + c0];
        }
    }

    // partials -> LDS: s_part[px][k*4+q], row stride 40 (float4-aligned)
    float* sp = &s_part[lpx * ASTR + q];
    #pragma unroll
    for (int k = 0; k < KK; ++k) sp[k * 4] = a[k];
    __syncthreads();

    if (tid < 64) {                                // wave 0: reduce + softmax
        const float* rp = &s_part[lpx * ASTR];
        float v[KK];
        #pragma unroll
        for (int k = 0; k < KK; ++k) {
            float4 t = *(const float4*)(rp + k * 4);
            v[k] = bconv[k] + t.x + t.y + t.z + t.w;
        }
        float m = v[0];
        #pragma unroll
        for (int k = 1; k < KK; ++k) m = fmaxf(m, v[k]);
        float s = 0.f;
        #pragma unroll
        for (int k = 0; k < KK; ++k) { v[k] = __expf(v[k] - m); s += v[k]; }
        float r = 1.0f / s;

        float* apix = att + ((size_t)b * KK) * (HO * WO) + ho * WO + wo;
        #pragma unroll
        for (int k = 0; k < KK; ++k)
            apix[(size_t)k * (HO * WO)] = v[k] * r;
    }
}

// ======================= kernel B: weighted 3x3 gather =======================
// v6 (unchanged, measured ~31.8 us): LDS-free shuffle gather.
//  - wave task = (b, value row h, 8-channel chunk): 8192 waves (32/CU req).
//  - ALL 24 value-row loads hoisted & issued first, then 18 att loads,
//    then shuffles/FMA/stores.
//  - +-1 column neighbors via __shfl_up/down(.,1): edge-lane keep-own
//    semantics implement the replication clamp for free.
#define CHUNK 8
__global__ __launch_bounds__(256)
void la_gather(const float* __restrict__ value,  // [8,128,64,64]
               const float* __restrict__ att,    // [8,9,128,128]
               float* __restrict__ out)          // [8,128,128,128]
{
    const int tid   = threadIdx.x;
    const int lane  = tid & 63;                    // value column w
    const int wseq  = blockIdx.x * 4 + (tid >> 6); // 0..8191
    const int chunk = wseq & 15;                   // 8-channel chunk
    const int h     = (wseq >> 4) & 63;            // value row
    const int b     = wseq >> 10;                  // batch

    const int hm = (h > 0) ? h - 1 : 0;            // replication clamp, rows
    const int hp = (h < HV - 1) ? h + 1 : HV - 1;
    const float* vc  = value + ((size_t)b * CH + chunk * CHUNK) * (HV * WV) + lane;
    const float* prm = vc + hm * WV;
    const float* pr0 = vc + h  * WV;
    const float* prp = vc + hp * WV;

    // ---- phase 1: issue ALL value loads (24 independent) ----
    float vm[CHUNK], v0[CHUNK], vp[CHUNK];
    #pragma unroll
    for (int cc = 0; cc < CHUNK; ++cc) {
        vm[cc] = prm[(size_t)cc * (HV * WV)];
        v0[cc] = pr0[(size_t)cc * (HV * WV)];
        vp[cc] = prp[(size_t)cc * (HV * WV)];
    }

    // ---- phase 2: att for the 4 out px (2h,2h+1) x (2*lane, 2*lane+1) ----
    float a00[KK], a01[KK], a10[KK], a11[KK];
    {
        const float* ap = att + ((size_t)b * KK * HO + 2 * h) * WO + 2 * lane;
        #pragma unroll
        for (int k = 0; k < KK; ++k) {
            float2 r0 = *(const float2*)(ap + (size_t)k * (HO * WO));
            float2 r1 = *(const float2*)(ap + (size_t)k * (HO * WO) + WO);
            a00[k] = r0.x; a01[k] = r0.y;
            a10[k] = r1.x; a11[k] = r1.y;
        }
    }

    float* ob = out + (((size_t)b * CH + chunk * CHUNK) * HO + 2 * h) * WO + 2 * lane;

    // ---- phase 3: shuffles + FMA + stores ----
    #pragma unroll
    for (int cc = 0; cc < CHUNK; ++cc) {
        float tm = vm[cc], t0 = v0[cc], tp = vp[cc];
        // column neighbors; edge lanes keep own value == replication clamp
        float tmL = __shfl_up(tm, 1), tmR = __shfl_down(tm, 1);
        float t0L = __shfl_up(t0, 1), t0R = __shfl_down(t0, 1);
        float tpL = __shfl_up(tp, 1), tpR = __shfl_down(tp, 1);

        float s00 = tmL*a00[0] + tm*a00[1] + tmR*a00[2]
                  + t0L*a00[3] + t0*a00[4] + t0R*a00[5]
                  + tpL*a00[6] + tp*a00[7] + tpR*a00[8];
        float s01 = tmL*a01[0] + tm*a01[1] + tmR*a01[2]
                  + t0L*a01[3] + t0*a01[4] + t0R*a01[5]
                  + tpL*a01[6] + tp*a01[7] + tpR*a01[8];
        float s10 = tmL*a10[0] + tm*a10[1] + tmR*a10[2]
                  + t0L*a10[3] + t0*a10[4] + t0R*a10[5]
                  + tpL*a10[6] + tp*a10[7] + tpR*a10[8];
        float s11 = tmL*a11[0] + tm*a11[1] + tmR*a11[2]
                  + t0L*a11[3] + t0*a11[4] + t0R*a11[5]
                  + tpL*a11[6] + tp*a11[7] + tpR*a11[8];

        float* oc = ob + (size_t)cc * (HO * WO);
        float2 r0; r0.x = s00; r0.y = s01;
        float2 r1; r1.x = s10; r1.y = s11;
        *(float2*)oc        = r0;   // out row 2h
        *(float2*)(oc + WO) = r1;   // out row 2h+1
    }
}

// ================== fallback: proven single fused kernel (R1) ==================
#define CCH 8
__global__ __launch_bounds__(128)
void la_fused(const float* __restrict__ guide,
              const float* __restrict__ value,
              const float* __restrict__ wconv,
              const float* __restrict__ bconv,
              float* __restrict__ out)
{
    __shared__ float s_wT[CH * 12];
    __shared__ float s_haloF[CCH * 110];

    const int tid = threadIdx.x;
    const int blk = blockIdx.x;
    const int wt = blk & 7;
    const int ht = (blk >> 3) & 7;
    const int b  = blk >> 6;

    for (int i = tid; i < KK * CH; i += 128) {
        int k = i >> 7;
        int c = i & 127;
        s_wT[c * 12 + k] = wconv[i];
    }

    const int tlwp = tid & 7;
    const int tho  = tid >> 3;
    const int ho = ht * 16 + tho;
    const int wo = wt * 16 + tlwp * 2;

    const float* gpix = guide + (((size_t)b * CH) * HO + ho) * WO + wo;

    float att0[KK], att1[KK];
    #pragma unroll
    for (int k = 0; k < KK; ++k) {
        float2 g = *(const float2*)(gpix + (size_t)k * (HO * WO));
        float bc = bconv[k];
        att0[k] = bc + g.x;
        att1[k] = bc + g.y;
    }
    __syncthreads();

    #pragma unroll 4
    for (int c = 0; c < CH; ++c) {
        float2 g = *(const float2*)(gpix + (size_t)c * (HO * WO));
        const float4* wt4 = (const float4*)&s_wT[c * 12];
        float4 wa = wt4[0];
        float4 wb = wt4[1];
        float w8 = s_wT[c * 12 + 8];
        att0[0] += g.x * wa.x;  att1[0] += g.y * wa.x;
        att0[1] += g.x * wa.y;  att1[1] += g.y * wa.y;
        att0[2] += g.x * wa.z;  att1[2] += g.y * wa.z;
        att0[3] += g.x * wa.w;  att1[3] += g.y * wa.w;
        att0[4] += g.x * wb.x;  att1[4] += g.y * wb.x;
        att0[5] += g.x * wb.y;  att1[5] += g.y * wb.y;
        att0[6] += g.x * wb.z;  att1[6] += g.y * wb.z;
        att0[7] += g.x * wb.w;  att1[7] += g.y * wb.w;
        att0[8] += g.x * w8;    att1[8] += g.y * w8;
    }

    float m0 = att0[0], m1 = att1[0];
    #pragma unroll
    for (int k = 1; k < KK; ++k) { m0 = fmaxf(m0, att0[k]); m1 = fmaxf(m1, att1[k]); }
    float s0 = 0.f, s1 = 0.f;
    #pragma unroll
    for (int k = 0; k < KK; ++k) {
        att0[k] = __expf(att0[k] - m0); s0 += att0[k];
        att1[k] = __expf(att1[k] - m1); s1 += att1[k];
    }
    float r0 = 1.0f / s0, r1 = 1.0f / s1;
    #pragma unroll
    for (int k = 0; k < KK; ++k) { att0[k] *= r0; att1[k] *= r1; }

    const int h0 = ht * 8 - 1;
    const int w0 = wt * 8 - 1;
    const int lh = tho >> 1;
    const float* vb = value + (size_t)b * CH * (HV * WV);
    float* ob = out + (((size_t)b * CH) * HO + ho) * WO + wo;

    for (int c0 = 0; c0 < CH; c0 += CCH) {
        __syncthreads();
        for (int i = tid; i < CCH * 100; i += 128) {
            int cc = i / 100;
            int r  = i - cc * 100;
            int hr = r / 10;
            int wr = r - hr * 10;
            int hh = min(max(h0 + hr, 0), HV - 1);
            int ww = min(max(w0 + wr, 0), WV - 1);
            s_haloF[cc * 110 + hr * 11 + wr] =
                vb[(size_t)(c0 + cc) * (HV * WV) + hh * WV + ww];
        }
        __syncthreads();
        #pragma unroll
        for (int cc = 0; cc < CCH; ++cc) {
            const float* hp = &s_haloF[cc * 110 + lh * 11 + tlwp];
            float v, q0, q1;
            v = hp[0];  q0  = v * att0[0]; q1  = v * att1[0];
            v = hp[1];  q0 += v * att0[1]; q1 += v * att1[1];
            v = hp[2];  q0 += v * att0[2]; q1 += v * att1[2];
            v = hp[11]; q0 += v * att0[3]; q1 += v * att1[3];
            v = hp[12]; q0 += v * att0[4]; q1 += v * att1[4];
            v = hp[13]; q0 += v * att0[5]; q1 += v * att1[5];
            v = hp[22]; q0 += v * att0[6]; q1 += v * att1[6];
            v = hp[23]; q0 += v * att0[7]; q1 += v * att1[7];
            v = hp[24]; q0 += v * att0[8]; q1 += v * att1[8];
            float2 rr; rr.x = q0; rr.y = q1;
            *(float2*)(ob + (size_t)(c0 + cc) * (HO * WO)) = rr;
        }
    }
}

extern "C" void kernel_launch(void* const* d_in, const int* in_sizes, int n_in,
                              void* d_out, int out_size, void* d_ws, size_t ws_size,
                              hipStream_t stream) {
    const float* guide = (const float*)d_in[0];
    const float* value = (const float*)d_in[1];
    const float* wconv = (const float*)d_in[2];
    const float* bconv = (const float*)d_in[3];
    float* outp = (float*)d_out;
    (void)in_sizes; (void)n_in; (void)out_size;

    const size_t att_bytes = (size_t)NB * KK * HO * WO * sizeof(float);  // 4.72 MB
    if (ws_size >= att_bytes) {
        float* attp = (float*)d_ws;
        la_att<<<dim3(2048), dim3(256), 0, stream>>>(guide, wconv, bconv, attp);
        la_gather<<<dim3(2048), dim3(256), 0, stream>>>(value, attp, outp);
    } else {
        la_fused<<<dim3(NB * 8 * 8), dim3(128), 0, stream>>>(guide, value, wconv, bconv, outp);
    }
}